// Round 24
// baseline (172.584 us; speedup 1.0000x reference)
//
#include <hip/hip_runtime.h>
#include <math.h>

typedef __attribute__((ext_vector_type(8))) short bf16x8;   // 8 bf16 (4 VGPRs)
typedef __attribute__((ext_vector_type(4))) float f32x4;    // MFMA C/D frag
typedef __attribute__((ext_vector_type(4))) unsigned short u16x4;
typedef __attribute__((ext_vector_type(8))) unsigned short u16x8;

#define MROWS 3088      // N tokens
#define NCTX  2064      // context rows/cols (N - Q)
#define NQ    1024
#define HEADS 12
#define QCH   16        // max 64-row chunks per object (robustness)
#define NCTXB 1584      // ctx blocks: 33 qt x 12 h x 4 column-slices
#define P3SPLIT 24576   // slice-3 partials: tasks < P3SPLIT in wqkv region (exact fit)
#define SC2   0.1803368801111f   // 0.125 * log2(e): softmax in base-2 domain

__device__ __forceinline__ ushort f2bf(float f){
  union { float f; unsigned u; } c; c.f = f;
  unsigned r = c.u + 0x7fffu + ((c.u >> 16) & 1u);   // RNE
  return (ushort)(r >> 16);
}
__device__ __forceinline__ float bf2f(ushort u){
  union { unsigned u; float f; } c; c.u = ((unsigned)u) << 16;
  return c.f;
}
__device__ __forceinline__ float ex2(float x){ return __builtin_amdgcn_exp2f(x); }
__device__ __forceinline__ unsigned cvtpk(float lo, float hi){
  unsigned r;
  asm("v_cvt_pk_bf16_f32 %0, %1, %2" : "=v"(r) : "v"(lo), "v"(hi));
  return r;
}
__device__ __forceinline__ float gelu_f(float x){
  return 0.5f * x * (1.0f + erff(x * 0.7071067811865475f));
}
__device__ __forceinline__ void gll16(const ushort* src, char* ldsdst){
  __builtin_amdgcn_global_load_lds((const __attribute__((address_space(1))) void*)src,
                                   (__attribute__((address_space(3))) void*)ldsdst, 16, 0, 0);
}

// ---------------- prep: wconv(qkv only) + ln1 + seg_minmax + bucketing ------
__global__ __launch_bounds__(256) void prep(
    const float* __restrict__ w0, ushort* __restrict__ o0,
    const float* __restrict__ x, const float* __restrict__ lnw,
    const float* __restrict__ lnb, ushort* __restrict__ xn,
    const int* __restrict__ patch_idx, const int* __restrict__ point_idx,
    int* __restrict__ pmm)
{
  const int b = blockIdx.x;
  const int t = threadIdx.x;
  if (b < 1728) {                              // ---- qkv weight convert
    int c = b * 256 + t;                       // c < 442368
    f32x4 v = *(const f32x4*)(w0 + (size_t)c * 4);
    u16x4 r;
    r[0] = f2bf(v[0]); r[1] = f2bf(v[1]); r[2] = f2bf(v[2]); r[3] = f2bf(v[3]);
    *(u16x4*)(o0 + (size_t)c * 4) = r;
  } else if (b < 1728 + 3088) {                // ---- layernorm 1
    int row = b - 1728;
    const float* xr = x + (size_t)row * 768;
    float v0 = xr[t], v1 = xr[t + 256], v2 = xr[t + 512];
    float s = v0 + v1 + v2;
    float ss = v0 * v0 + v1 * v1 + v2 * v2;
#pragma unroll
    for (int o = 32; o >= 1; o >>= 1) { s += __shfl_xor(s, o); ss += __shfl_xor(ss, o); }
    __shared__ float red[8];
    int wv = t >> 6;
    if ((t & 63) == 0) { red[wv] = s; red[4 + wv] = ss; }
    __syncthreads();
    s = red[0] + red[1] + red[2] + red[3];
    ss = red[4] + red[5] + red[6] + red[7];
    float mean = s * (1.0f / 768.0f);
    float var = ss * (1.0f / 768.0f) - mean * mean;
    float rstd = rsqrtf(var + 1e-5f);
    ushort* orow = xn + (size_t)row * 768;
    orow[t]       = f2bf((v0 - mean) * rstd * lnw[t]       + lnb[t]);
    orow[t + 256] = f2bf((v1 - mean) * rstd * lnw[t + 256] + lnb[t + 256]);
    orow[t + 512] = f2bf((v2 - mean) * rstd * lnw[t + 512] + lnb[t + 512]);
  } else {                                     // ---- seg min/max + bucketing
    __shared__ int smin[16], smax[16], hcnt[16], hoff[16], hcur[16];
    if (t < 16) { smin[t] = 0x7fffffff; smax[t] = -1; hcnt[t] = 0; }
    __syncthreads();
    for (int i = t; i < 2048; i += 256) {
      int o = patch_idx[i];
      atomicMin(&smin[o], i);
      atomicMax(&smax[o], i);
    }
    for (int i = t; i < 1024; i += 256)
      atomicAdd(&hcnt[point_idx[i]], 1);
    __syncthreads();
    if (t == 0) {
      int acc = 0;
      for (int o = 0; o < 16; o++) { hoff[o] = acc; hcur[o] = acc; acc += hcnt[o]; }
    }
    __syncthreads();
    for (int i = t; i < 1024; i += 256) {
      int o = point_idx[i];
      int p = atomicAdd(&hcur[o], 1);
      pmm[64 + p] = i;                         // qidx
    }
    if (t < 16) {
      pmm[t]      = (smin[t] == 0x7fffffff) ? (1 << 30) : smin[t] + 16;  // lo
      pmm[16 + t] = smax[t] + 16;                                        // hi
      pmm[32 + t] = hoff[t];                                             // qoff
      pmm[48 + t] = hcnt[t];                                             // qcnt
    }
  }
}

// ---------------- layernorm + d_out init (x1 + fc2 bias) --------------------
__global__ __launch_bounds__(256) void ln_k(const float* __restrict__ x,
                                            const float* __restrict__ w,
                                            const float* __restrict__ b,
                                            ushort* __restrict__ out,
                                            const float* __restrict__ fc2b,
                                            float* __restrict__ dinit)
{
  int row = blockIdx.x, t = threadIdx.x;
  const float* xr = x + (size_t)row * 768;
  float v0 = xr[t], v1 = xr[t + 256], v2 = xr[t + 512];
  float s = v0 + v1 + v2;
  float ss = v0 * v0 + v1 * v1 + v2 * v2;
#pragma unroll
  for (int o = 32; o >= 1; o >>= 1) { s += __shfl_xor(s, o); ss += __shfl_xor(ss, o); }
  __shared__ float red[8];
  int wv = t >> 6;
  if ((t & 63) == 0) { red[wv] = s; red[4 + wv] = ss; }
  __syncthreads();
  s = red[0] + red[1] + red[2] + red[3];
  ss = red[4] + red[5] + red[6] + red[7];
  float mean = s * (1.0f / 768.0f);
  float var = ss * (1.0f / 768.0f) - mean * mean;
  float rstd = rsqrtf(var + 1e-5f);
  ushort* orow = out + (size_t)row * 768;
  orow[t]       = f2bf((v0 - mean) * rstd * w[t]       + b[t]);
  orow[t + 256] = f2bf((v1 - mean) * rstd * w[t + 256] + b[t + 256]);
  orow[t + 512] = f2bf((v2 - mean) * rstd * w[t + 512] + b[t + 512]);
  float* drow = dinit + (size_t)row * 768;     // fc2 split-K accumulator base
  drow[t]       = v0 + fc2b[t];
  drow[t + 256] = v1 + fc2b[t + 256];
  drow[t + 512] = v2 + fc2b[t + 512];
}

// ---------------- MFMA GEMM 128x128, BK=32 (qkv, fc1) -----------------------
// MODE 0: qkv scatter -> q/k/v [12][3088][64] bf16 + vT [12][64][3088] bf16
// MODE 2: bf16 out = gelu(acc + bias[col])                  (stride 3072)
template<int MODE, int BM, int BN, int KSPLIT>
__global__ __launch_bounds__(256, 2) void gemmk(
    const ushort* __restrict__ A, const ushort* __restrict__ Bw, int K,
    ushort* __restrict__ oq, ushort* __restrict__ ok,
    ushort* __restrict__ ov, ushort* __restrict__ ovt,
    float* __restrict__ of, const float* __restrict__ bias,
    const float* __restrict__ resid, ushort* __restrict__ oh)
{
  constexpr int MF = (BM == 64 && BN == 64) ? 2 : 4;
  constexpr int NF = (BM == 128 && BN == 128) ? 4 : 2;
  constexpr int GLLS = BM / 64 + BN / 64;      // gll per thread per stage
  constexpr int ABUF = BM * 64;                // bytes per A buffer
  constexpr int BBUF = BN * 64;
  __shared__ ushort ldsA[3 * BM * 32];
  __shared__ ushort ldsB[3 * BN * 32];
  const int tid = threadIdx.x;
  const int lane = tid & 63;
  const int wv = tid >> 6;
  const int g = lane >> 4, lq = lane & 15;

  // XCD swizzle: hw linear d -> logical l (x-major), chunked per XCD
  const int nwg = gridDim.x * gridDim.y;
  const int d = blockIdx.y * gridDim.x + blockIdx.x;
  const int qq = nwg >> 3, rr = nwg & 7, xcd = d & 7, ii = d >> 3;
  const int l = (xcd < rr ? xcd * (qq + 1) : rr * (qq + 1) + (xcd - rr) * qq) + ii;
  const int bx = l % gridDim.x, byl = l / gridDim.x;

  const int ybl = gridDim.y / KSPLIT;
  const int ks = (KSPLIT == 2) ? (byl / ybl) : 0;
  const int by = byl - ks * ybl;
  const int k0 = ks * (K / KSPLIT);
  const int klen = K / KSPLIT;

  const int row0 = by * BM, col0 = bx * BN;
  const int wrow = (BM == 128) ? (wv >> 1) * 64 : ((BN == 64) ? (wv >> 1) * 32 : 0);
  const int wcol = (BM == 128) ? (wv & 1) * 64 : ((BN == 64) ? (wv & 1) * 32 : wv * 32);

  f32x4 acc[MF][NF] = {};

  const int rS = tid >> 2;
  const int cS = (tid & 3) ^ ((rS >> 1) & 3);
  int arow0 = row0 + rS;       if (arow0 > MROWS - 1) arow0 = MROWS - 1;
  int arow1 = row0 + 64 + rS;  if (arow1 > MROWS - 1) arow1 = MROWS - 1;
  const ushort* srcA0 = A + (size_t)arow0 * K + k0 + cS * 8;
  const ushort* srcA1 = A + (size_t)arow1 * K + k0 + cS * 8;   // BM==128 only
  const ushort* srcB0 = Bw + (size_t)(col0 + rS) * K + k0 + cS * 8;
  const ushort* srcB1 = Bw + (size_t)(col0 + 64 + rS) * K + k0 + cS * 8;

  auto STAGE = [&](int kk, int buf) {
    char* ab = (char*)ldsA + buf * ABUF + wv * 1024;
    char* bb = (char*)ldsB + buf * BBUF + wv * 1024;
    gll16(srcA0 + kk, ab);
    if constexpr (BM == 128) gll16(srcA1 + kk, ab + 4096);
    gll16(srcB0 + kk, bb);
    if constexpr (BN == 128) gll16(srcB1 + kk, bb + 4096);
  };

  const int nIter = klen >> 5;
  STAGE(0, 0);
  STAGE(32, 1);
  int bufc = 0;
  for (int t = 0; t < nIter; t++) {
    if (t + 2 < nIter) {
      int bn = bufc + 2; if (bn >= 3) bn -= 3;
      STAGE((t + 2) << 5, bn);
      asm volatile("s_waitcnt vmcnt(%0)" :: "i"(2 * GLLS) : "memory");
    } else if (t + 1 < nIter) {
      asm volatile("s_waitcnt vmcnt(%0)" :: "i"(GLLS) : "memory");
    } else {
      asm volatile("s_waitcnt vmcnt(0)" ::: "memory");
    }
    __builtin_amdgcn_s_barrier();

    const char* pa = (char*)ldsA + bufc * ABUF;
    const char* pb = (char*)ldsB + bufc * BBUF;
    bf16x8 af[MF], bfr[NF];
#pragma unroll
    for (int mf = 0; mf < MF; mf++) {
      int r = wrow + mf * 16 + lq;
      af[mf] = *(const bf16x8*)(pa + r * 64 + ((g ^ ((r >> 1) & 3)) << 4));
    }
#pragma unroll
    for (int nf = 0; nf < NF; nf++) {
      int c = wcol + nf * 16 + lq;
      bfr[nf] = *(const bf16x8*)(pb + c * 64 + ((g ^ ((c >> 1) & 3)) << 4));
    }
#pragma unroll
    for (int mf = 0; mf < MF; mf++)
#pragma unroll
      for (int nf = 0; nf < NF; nf++)
        acc[mf][nf] = __builtin_amdgcn_mfma_f32_16x16x32_bf16(af[mf], bfr[nf], acc[mf][nf], 0, 0, 0);
    __builtin_amdgcn_s_barrier();
    bufc++; if (bufc >= 3) bufc = 0;
  }

  // epilogue: C frag layout col = lane&15, row = (lane>>4)*4 + reg   [m89]
#pragma unroll
  for (int mf = 0; mf < MF; mf++) {
    int rowb = row0 + wrow + mf * 16 + g * 4;
    if (rowb >= MROWS) continue;
#pragma unroll
    for (int nf = 0; nf < NF; nf++) {
      int col = col0 + wcol + nf * 16 + lq;
      if (MODE == 0) {
        int which = col / 768;
        int rem = col - which * 768;
        int hd = rem >> 6, dd = rem & 63;
        size_t base = ((size_t)hd * MROWS + rowb) * 64 + dd;
        ushort b0 = f2bf(acc[mf][nf][0]);
        ushort b1 = f2bf(acc[mf][nf][1]);
        ushort b2 = f2bf(acc[mf][nf][2]);
        ushort b3 = f2bf(acc[mf][nf][3]);
        ushort* dst = (which == 0) ? oq : (which == 1) ? ok : ov;
        dst[base] = b0; dst[base + 64] = b1; dst[base + 128] = b2; dst[base + 192] = b3;
        if (which == 2) {
          u16x4 pk; pk[0] = b0; pk[1] = b1; pk[2] = b2; pk[3] = b3;
          *(u16x4*)&ovt[((size_t)hd * 64 + dd) * MROWS + rowb] = pk;   // V^T
        }
      } else if (MODE == 1) {
#pragma unroll
        for (int r = 0; r < 4; r++) {
          size_t idx = (size_t)(rowb + r) * 768 + col;
          of[idx] = acc[mf][nf][r] + bias[col] + resid[idx];
        }
      } else {
#pragma unroll
        for (int r = 0; r < 4; r++) {
          size_t idx = (size_t)(rowb + r) * 3072 + col;
          oh[idx] = f2bf(gelu_f(acc[mf][nf][r] + bias[col]));
        }
      }
    }
  }
}

// ---------------- MFMA GEMM 64x64, BK=64 (proj, fc2) ------------------------
// Triple-buffered (prefetch depth 2), 2 barriers/iter — BEST MEASURED (R16).
// KSPLIT=2 pairs the two K-halves of an output tile on ADJACENT logical ids
// (ks = byl&1, same XCD): second atomicAdd hits that XCD's L2.
// MODE 1: fp32 out = acc+bias+resid. MODE 4: atomicAdd fp32 (init preloaded).
template<int MODE, int KSPLIT>
__global__ __launch_bounds__(256, 2) void gemm64(
    const ushort* __restrict__ A, const ushort* __restrict__ Bw, int K,
    float* __restrict__ of, const float* __restrict__ bias,
    const float* __restrict__ resid)
{
  __shared__ ushort ldsA[3 * 64 * 64];         // 24 KB
  __shared__ ushort ldsB[3 * 64 * 64];         // 24 KB
  const int tid = threadIdx.x;
  const int lane = tid & 63;
  const int wv = tid >> 6;
  const int g = lane >> 4, lq = lane & 15;

  // XCD swizzle (bijective, m204)
  const int nwg = gridDim.x * gridDim.y;
  const int d = blockIdx.y * gridDim.x + blockIdx.x;
  const int qq = nwg >> 3, rr = nwg & 7, xcd = d & 7, ii = d >> 3;
  const int l = (xcd < rr ? xcd * (qq + 1) : rr * (qq + 1) + (xcd - rr) * qq) + ii;
  const int bx = l % gridDim.x, byl = l / gridDim.x;
  const int ks = (KSPLIT > 1) ? (byl & (KSPLIT - 1)) : 0;    // K-slices adjacent
  const int by = (KSPLIT > 1) ? (byl / KSPLIT) : byl;
  const int k0 = ks * (K / KSPLIT);
  const int klen = K / KSPLIT;

  const int row0 = by * 64, col0 = bx * 64;
  const int wrow = (wv >> 1) * 32, wcol = (wv & 1) * 32;

  f32x4 acc[2][2] = {};

  const int rA0 = tid >> 3;
  const int cL  = (tid & 7) ^ (rA0 & 7);       // same for rA0+32 (32 = 0 mod 8)
  int ar0 = row0 + rA0;       if (ar0 > MROWS - 1) ar0 = MROWS - 1;
  int ar1 = row0 + rA0 + 32;  if (ar1 > MROWS - 1) ar1 = MROWS - 1;
  const ushort* sA0 = A + (size_t)ar0 * K + k0 + cL * 8;
  const ushort* sA1 = A + (size_t)ar1 * K + k0 + cL * 8;
  const ushort* sB0 = Bw + (size_t)(col0 + rA0) * K + k0 + cL * 8;
  const ushort* sB1 = Bw + (size_t)(col0 + rA0 + 32) * K + k0 + cL * 8;

  auto STAGE = [&](int kk, int buf) {
    char* ab = (char*)ldsA + buf * 8192 + wv * 1024;
    char* bb = (char*)ldsB + buf * 8192 + wv * 1024;
    gll16(sA0 + kk, ab);
    gll16(sA1 + kk, ab + 4096);
    gll16(sB0 + kk, bb);
    gll16(sB1 + kk, bb + 4096);
  };

  const int nIter = klen >> 6;
  STAGE(0, 0);
  STAGE(64, 1);
  int bufc = 0;
  for (int t = 0; t < nIter; t++) {
    if (t + 2 < nIter) {
      int bn = bufc + 2; if (bn >= 3) bn -= 3;
      STAGE((t + 2) << 6, bn);
      asm volatile("s_waitcnt vmcnt(8)" ::: "memory");
    } else if (t + 1 < nIter) {
      asm volatile("s_waitcnt vmcnt(4)" ::: "memory");
    } else {
      asm volatile("s_waitcnt vmcnt(0)" ::: "memory");
    }
    __builtin_amdgcn_s_barrier();

    const char* pa = (char*)ldsA + bufc * 8192;
    const char* pb = (char*)ldsB + bufc * 8192;
    bf16x8 af[2][2], bfr[2][2];
#pragma unroll
    for (int mf = 0; mf < 2; mf++) {
      int r = wrow + mf * 16 + lq;
#pragma unroll
      for (int k2 = 0; k2 < 2; k2++)
        af[mf][k2] = *(const bf16x8*)(pa + r * 128 + ((((k2 << 2) + g) ^ (r & 7)) << 4));
    }
#pragma unroll
    for (int nf = 0; nf < 2; nf++) {
      int c = wcol + nf * 16 + lq;
#pragma unroll
      for (int k2 = 0; k2 < 2; k2++)
        bfr[nf][k2] = *(const bf16x8*)(pb + c * 128 + ((((k2 << 2) + g) ^ (c & 7)) << 4));
    }
#pragma unroll
    for (int mf = 0; mf < 2; mf++)
#pragma unroll
      for (int nf = 0; nf < 2; nf++) {
        acc[mf][nf] = __builtin_amdgcn_mfma_f32_16x16x32_bf16(af[mf][0], bfr[nf][0], acc[mf][nf], 0, 0, 0);
        acc[mf][nf] = __builtin_amdgcn_mfma_f32_16x16x32_bf16(af[mf][1], bfr[nf][1], acc[mf][nf], 0, 0, 0);
      }
    __builtin_amdgcn_s_barrier();
    bufc++; if (bufc >= 3) bufc = 0;
  }

  // epilogue: C frag layout col = lane&15, row = (lane>>4)*4 + reg   [m89]
#pragma unroll
  for (int mf = 0; mf < 2; mf++) {
    int rowb = row0 + wrow + mf * 16 + g * 4;
    if (rowb >= MROWS) continue;
#pragma unroll
    for (int nf = 0; nf < 2; nf++) {
      int col = col0 + wcol + nf * 16 + lq;
      if (MODE == 1) {
#pragma unroll
        for (int r = 0; r < 4; r++) {
          size_t idx = (size_t)(rowb + r) * 768 + col;
          of[idx] = acc[mf][nf][r] + bias[col] + resid[idx];
        }
      } else {
#pragma unroll
        for (int r = 0; r < 4; r++) {
          size_t idx = (size_t)(rowb + r) * 768 + col;
          atomicAdd(&of[idx], acc[mf][nf][r]);
        }
      }
    }
  }
}

// ---------------- fused attention (+ wconv tail for proj/fc1/fc2) -----------
// ctx: 4-way COLUMN split — slice 0: 9 tiles, slices 1..3: 8 tiles (sum 33).
// Partials (entry = 72 ushorts = 144 B; 24768 tasks):
//   slices 0,1 -> part01[(task*2+slice)*72]            (7.13 MB of 9.49 MB x1)
//   slice 2    -> part2[task*72]                       (3.57 MB of 4.74 MB xn)
//   slice 3    -> task<24576: part3a[task*72]          (wqkv region, EXACT fit:
//                 24576*144 = 3538944 B = wqkv size; dead after qkv-GEMM)
//                 else: part01 + 3566592 + (task-24576)*72   (x1 tail slack)
// Softmax in BASE-2 domain (SC2 pre-scale, raw v_exp_f32, m/l in log2).
__global__ __launch_bounds__(256) void attn_fused(
    const ushort* __restrict__ qarr, const ushort* __restrict__ karr,
    const ushort* __restrict__ varr, const ushort* __restrict__ vt,
    const int* __restrict__ pmm, ushort* __restrict__ part01,
    ushort* __restrict__ part2, ushort* __restrict__ part3a,
    ushort* __restrict__ attn_out,
    const float* __restrict__ cw1, const float* __restrict__ cw2,
    const float* __restrict__ cw3, ushort* __restrict__ cd1,
    ushort* __restrict__ cd2, ushort* __restrict__ cd3)
{
  __shared__ ushort ldsK[2][64 * 64];
  __shared__ ushort ldsV[2][64 * 64];
  const int tid = threadIdx.x;
  const int lane = tid & 63;
  const int wv = tid >> 6;
  const int b = blockIdx.x;
  const int g = lane >> 4, lq = lane & 15;

  if (b >= NCTXB + 3072) {                     // ============ weight convert
    int c = 442368 + (b - NCTXB - 3072) * 256 + tid;
    const float* src; ushort* dst; int i;
    if (c < 589824)       { src = cw1; dst = cd1; i = c - 442368; }   // proj
    else if (c < 1179648) { src = cw2; dst = cd2; i = c - 589824; }   // fc1
    else                  { src = cw3; dst = cd3; i = c - 1179648; }  // fc2
    f32x4 v = *(const f32x4*)(src + (size_t)i * 4);
    u16x4 r;
    r[0] = f2bf(v[0]); r[1] = f2bf(v[1]); r[2] = f2bf(v[2]); r[3] = f2bf(v[3]);
    *(u16x4*)(dst + (size_t)i * 4) = r;
    return;
  }

  // common staging geometry
  const int n0 = tid, n1 = 256 + tid;
  const int r0s = n0 >> 3, c0s = (n0 & 7) ^ (r0s & 3) ^ (((r0s >> 3) & 1) << 2);
  const int r1s = n1 >> 3, c1s = (n1 & 7) ^ (r1s & 3) ^ (((r1s >> 3) & 1) << 2);
  char* dk0 = (char*)&ldsK[0][0] + wv * 1024;
  char* dv0 = (char*)&ldsV[0][0] + wv * 1024;

  auto ldK = [&](int buf, int r, int c) -> bf16x8 {
    int cs = c ^ (r & 3) ^ (((r >> 3) & 1) << 2);
    return *(const bf16x8*)&ldsK[buf][r * 64 + cs * 8];
  };
  auto ldV = [&](int buf, int r, int c) -> bf16x8 {
    int cs = c ^ (r & 3) ^ (((r >> 3) & 1) << 2);
    return *(const bf16x8*)&ldsV[buf][r * 64 + cs * 8];
  };
  const int kfr0 = (lq >> 2) * 8 + (lq & 3);   // A-frag row perm

  if (b < NCTXB) {                             // ================= context
    // bijective XCD swizzle over 1584 blocks (1584 = 8*198 exactly);
    // logical l = h*132 + qt*4 + slice
    const int xcd = b & 7, ii = b >> 3;
    const int l = xcd * 198 + ii;
    const int h = l / 132;
    const int rem = l - h * 132;
    const int qt = rem >> 2, slice = rem & 3;
    const int qrow = qt * 64 + wv * 16 + lq;
    const int qload = qrow < NCTX ? qrow : NCTX - 1;
    const size_t hb = (size_t)h * MROWS;

    const ushort* qb = qarr + (hb + qload) * 64 + g * 8;
    bf16x8 qf0 = *(const bf16x8*)qb;
    bf16x8 qf1 = *(const bf16x8*)(qb + 32);

    auto STAGE = [&](int t, int buf) {
      int cb = t * 64;
      int kr0 = cb + r0s; if (kr0 > NCTX - 1) kr0 = NCTX - 1;
      int kr1 = cb + r1s; if (kr1 > NCTX - 1) kr1 = NCTX - 1;
      char* dk = dk0 + buf * 8192;
      char* dv = dv0 + buf * 8192;
      gll16(karr + (hb + kr0) * 64 + c0s * 8, dk);
      gll16(karr + (hb + kr1) * 64 + c1s * 8, dk + 4096);
      gll16(vt + ((size_t)h * 64 + r0s) * MROWS + cb + c0s * 8, dv);
      gll16(vt + ((size_t)h * 64 + r1s) * MROWS + cb + c1s * 8, dv + 4096);
    };

    float m = -1e30f, lsum = 0.0f;
    f32x4 o[4] = {};

    const int t0 = slice * 8 + (slice > 0 ? 1 : 0);   // {0,9,17,25}
    const int nt = 8 + (slice == 0 ? 1 : 0);          // {9,8,8,8}; sum = 33
    STAGE(t0, 0);
    for (int ti = 0; ti < nt; ti++) {
      const int t = t0 + ti;
      const int cur = ti & 1;
      if (ti + 1 < nt) {
        STAGE(t + 1, cur ^ 1);
        asm volatile("s_waitcnt vmcnt(4)" ::: "memory");
      } else {
        asm volatile("s_waitcnt vmcnt(0)" ::: "memory");
      }
      __builtin_amdgcn_s_barrier();

      const int cb = t * 64;
      float s[16];
#pragma unroll
      for (int hf = 0; hf < 2; hf++) {
        int rb = hf * 32 + kfr0;
        bf16x8 ka00 = ldK(cur, rb, g);
        bf16x8 ka01 = ldK(cur, rb, g + 4);
        bf16x8 ka10 = ldK(cur, rb + 4, g);
        bf16x8 ka11 = ldK(cur, rb + 4, g + 4);
        f32x4 st0 = {0.f, 0.f, 0.f, 0.f}, st1 = {0.f, 0.f, 0.f, 0.f};
        st0 = __builtin_amdgcn_mfma_f32_16x16x32_bf16(ka00, qf0, st0, 0, 0, 0);
        st0 = __builtin_amdgcn_mfma_f32_16x16x32_bf16(ka01, qf1, st0, 0, 0, 0);
        st1 = __builtin_amdgcn_mfma_f32_16x16x32_bf16(ka10, qf0, st1, 0, 0, 0);
        st1 = __builtin_amdgcn_mfma_f32_16x16x32_bf16(ka11, qf1, st1, 0, 0, 0);
#pragma unroll
        for (int r = 0; r < 4; r++) {
          s[hf * 8 + r] = st0[r] * SC2;
          s[hf * 8 + 4 + r] = st1[r] * SC2;
        }
      }
      if (cb + 64 > NCTX) {
#pragma unroll
        for (int hf = 0; hf < 2; hf++)
          if (cb + hf * 32 + g * 8 >= NCTX) {
#pragma unroll
            for (int j = 0; j < 8; j++) s[hf * 8 + j] = -1e30f;
          }
      }
      float tm = s[0];
#pragma unroll
      for (int j = 1; j < 16; j++) tm = fmaxf(tm, s[j]);
      tm = fmaxf(tm, __shfl_xor(tm, 16));
      tm = fmaxf(tm, __shfl_xor(tm, 32));
      float nm = fmaxf(m, tm);
      bool resc = !__all(tm <= m);             // skip rescale if max unchanged
      float p[16], ps = 0.f;
#pragma unroll
      for (int j = 0; j < 16; j++) { p[j] = ex2(s[j] - nm); ps += p[j]; }
      ps += __shfl_xor(ps, 16);
      ps += __shfl_xor(ps, 32);
      if (resc) {
        float alpha = ex2(m - nm);
        lsum = lsum * alpha;
#pragma unroll
        for (int mf = 0; mf < 4; mf++) {
          o[mf][0] *= alpha; o[mf][1] *= alpha; o[mf][2] *= alpha; o[mf][3] *= alpha;
        }
      }
      lsum += ps;
      m = nm;
#pragma unroll
      for (int hf = 0; hf < 2; hf++) {
        union { bf16x8 v; unsigned u[4]; } pb;
        pb.u[0] = cvtpk(p[hf * 8 + 0], p[hf * 8 + 1]);
        pb.u[1] = cvtpk(p[hf * 8 + 2], p[hf * 8 + 3]);
        pb.u[2] = cvtpk(p[hf * 8 + 4], p[hf * 8 + 5]);
        pb.u[3] = cvtpk(p[hf * 8 + 6], p[hf * 8 + 7]);
#pragma unroll
        for (int mf = 0; mf < 4; mf++) {
          bf16x8 va = ldV(cur, mf * 16 + lq, hf * 4 + g);
          o[mf] = __builtin_amdgcn_mfma_f32_16x16x32_bf16(va, pb.v, o[mf], 0, 0, 0);
        }
      }
      __builtin_amdgcn_s_barrier();
    }

    if (qrow < NCTX) {                         // write partial (o bf16, m, l)
      const int task = h * NCTX + qrow;
      ushort* pe;
      if (slice < 2)       pe = part01 + (size_t)((task << 1) + slice) * 72;
      else if (slice == 2) pe = part2 + (size_t)task * 72;
      else pe = (task < P3SPLIT) ? part3a + (size_t)task * 72
                                 : part01 + 3566592 + (size_t)(task - P3SPLIT) * 72;
#pragma unroll
      for (int mf = 0; mf < 4; mf++) {
        u16x4 pk;
        pk[0] = f2bf(o[mf][0]); pk[1] = f2bf(o[mf][1]);
        pk[2] = f2bf(o[mf][2]); pk[3] = f2bf(o[mf][3]);
        *(u16x4*)(pe + mf * 16 + g * 4) = pk;
      }
      if (g == 0) {
        float* fl = (float*)(pe + 64);
        fl[0] = m; fl[1] = lsum;               // m in log2 domain
      }
    }
  } else {                                     // ============ grouped queries
    const int idx = b - NCTXB;
    const int ch = idx / 192;                  // chunk-major: active blocks first
    const int oh = idx % 192;
    const int obj = oh & 15, h = oh >> 4;
    const int cnt = pmm[48 + obj];
    if (ch * 64 >= cnt) return;
    const int lo = pmm[obj], hi = pmm[16 + obj];
    const int qoff = pmm[32 + obj];
    const size_t hb = (size_t)h * MROWS;

    const int ridx = ch * 64 + wv * 16 + lq;
    const bool rvalid = ridx < cnt;
    const int qi = rvalid ? pmm[64 + qoff + ridx] : 0;
    const int grow = NCTX + qi;                // global token row

    const ushort* qb = qarr + (hb + grow) * 64 + g * 8;
    bf16x8 qf0 = *(const bf16x8*)qb;
    bf16x8 qf1 = *(const bf16x8*)(qb + 32);

    const int lo8 = lo & ~7;                   // 16B-align the column window
    const int ntiles = (hi - lo8 + 64) >> 6;   // covers [lo8, hi]

    auto STAGE = [&](int t, int buf) {
      int cb = lo8 + t * 64;
      int kr0 = cb + r0s; if (kr0 > MROWS - 1) kr0 = MROWS - 1;
      int kr1 = cb + r1s; if (kr1 > MROWS - 1) kr1 = MROWS - 1;
      char* dk = dk0 + buf * 8192;
      char* dv = dv0 + buf * 8192;
      gll16(karr + (hb + kr0) * 64 + c0s * 8, dk);
      gll16(karr + (hb + kr1) * 64 + c1s * 8, dk + 4096);
      gll16(vt + ((size_t)h * 64 + r0s) * MROWS + cb + c0s * 8, dv);
      gll16(vt + ((size_t)h * 64 + r1s) * MROWS + cb + c1s * 8, dv + 4096);
    };

    float m = -1e30f, lsum = 0.0f;
    f32x4 o[4] = {};

    STAGE(0, 0);
    for (int t = 0; t < ntiles; t++) {
      const int cur = t & 1;
      if (t + 1 < ntiles) {
        STAGE(t + 1, cur ^ 1);
        asm volatile("s_waitcnt vmcnt(4)" ::: "memory");
      } else {
        asm volatile("s_waitcnt vmcnt(0)" ::: "memory");
      }
      __builtin_amdgcn_s_barrier();

      const int cb = lo8 + t * 64;
      float s[16];
#pragma unroll
      for (int hf = 0; hf < 2; hf++) {
        int rb = hf * 32 + kfr0;
        bf16x8 ka00 = ldK(cur, rb, g);
        bf16x8 ka01 = ldK(cur, rb, g + 4);
        bf16x8 ka10 = ldK(cur, rb + 4, g);
        bf16x8 ka11 = ldK(cur, rb + 4, g + 4);
        f32x4 st0 = {0.f, 0.f, 0.f, 0.f}, st1 = {0.f, 0.f, 0.f, 0.f};
        st0 = __builtin_amdgcn_mfma_f32_16x16x32_bf16(ka00, qf0, st0, 0, 0, 0);
        st0 = __builtin_amdgcn_mfma_f32_16x16x32_bf16(ka01, qf1, st0, 0, 0, 0);
        st1 = __builtin_amdgcn_mfma_f32_16x16x32_bf16(ka10, qf0, st1, 0, 0, 0);
        st1 = __builtin_amdgcn_mfma_f32_16x16x32_bf16(ka11, qf1, st1, 0, 0, 0);
        int c0 = cb + hf * 32 + g * 8;
#pragma unroll
        for (int r = 0; r < 4; r++) {
          s[hf * 8 + r]     = (c0 + r >= lo && c0 + r <= hi) ? st0[r] * SC2 : -1e30f;
          s[hf * 8 + 4 + r] = (c0 + 4 + r >= lo && c0 + 4 + r <= hi) ? st1[r] * SC2 : -1e30f;
        }
      }
      float tm = s[0];
#pragma unroll
      for (int j = 1; j < 16; j++) tm = fmaxf(tm, s[j]);
      tm = fmaxf(tm, __shfl_xor(tm, 16));
      tm = fmaxf(tm, __shfl_xor(tm, 32));
      float nm = fmaxf(m, tm);
      bool resc = !__all(tm <= m);
      float p[16], ps = 0.f;
#pragma unroll
      for (int j = 0; j < 16; j++) { p[j] = ex2(s[j] - nm); ps += p[j]; }
      ps += __shfl_xor(ps, 16);
      ps += __shfl_xor(ps, 32);
      if (resc) {
        float alpha = ex2(m - nm);
        lsum = lsum * alpha;
#pragma unroll
        for (int mf = 0; mf < 4; mf++) {
          o[mf][0] *= alpha; o[mf][1] *= alpha; o[mf][2] *= alpha; o[mf][3] *= alpha;
        }
      }
      lsum += ps;
      m = nm;
#pragma unroll
      for (int hf = 0; hf < 2; hf++) {
        union { bf16x8 v; unsigned u[4]; } pb;
        pb.u[0] = cvtpk(p[hf * 8 + 0], p[hf * 8 + 1]);
        pb.u[1] = cvtpk(p[hf * 8 + 2], p[hf * 8 + 3]);
        pb.u[2] = cvtpk(p[hf * 8 + 4], p[hf * 8 + 5]);
        pb.u[3] = cvtpk(p[hf * 8 + 6], p[hf * 8 + 7]);
#pragma unroll
        for (int mf = 0; mf < 4; mf++) {
          bf16x8 va = ldV(cur, mf * 16 + lq, hf * 4 + g);
          o[mf] = __builtin_amdgcn_mfma_f32_16x16x32_bf16(va, pb.v, o[mf], 0, 0, 0);
        }
      }
      __builtin_amdgcn_s_barrier();
    }

    // ---- diag (own token) + object-token columns, merged per-row ----
    {
      const ushort* kd = karr + (hb + grow) * 64 + g * 8;
      const ushort* ko = karr + (hb + obj) * 64 + g * 8;
      bf16x8 kd0 = *(const bf16x8*)kd, kd1 = *(const bf16x8*)(kd + 32);
      bf16x8 ko0 = *(const bf16x8*)ko, ko1 = *(const bf16x8*)(ko + 32);
      float sd = 0.f, so = 0.f;
#pragma unroll
      for (int j = 0; j < 8; j++) {
        sd = fmaf(bf2f((ushort)qf0[j]), bf2f((ushort)kd0[j]), sd);
        sd = fmaf(bf2f((ushort)qf1[j]), bf2f((ushort)kd1[j]), sd);
        so = fmaf(bf2f((ushort)qf0[j]), bf2f((ushort)ko0[j]), so);
        so = fmaf(bf2f((ushort)qf1[j]), bf2f((ushort)ko1[j]), so);
      }
      sd += __shfl_xor(sd, 16); sd += __shfl_xor(sd, 32);
      so += __shfl_xor(so, 16); so += __shfl_xor(so, 32);
      sd *= SC2; so *= SC2;
      float nm = fmaxf(m, fmaxf(sd, so));
      float alpha = ex2(m - nm);
      float pd = ex2(sd - nm), po = ex2(so - nm);
      lsum = lsum * alpha + pd + po;
      float inv = 1.0f / lsum;
      if (rvalid) {
        ushort* ob = attn_out + (size_t)grow * 768 + h * 64;
#pragma unroll
        for (int mf = 0; mf < 4; mf++) {
          u16x4 vd = *(const u16x4*)&varr[(hb + grow) * 64 + mf * 16 + g * 4];
          u16x4 vo = *(const u16x4*)&varr[(hb + obj) * 64 + mf * 16 + g * 4];
          u16x4 pk;
#pragma unroll
          for (int r = 0; r < 4; r++)
            pk[r] = f2bf((o[mf][r] * alpha + pd * bf2f(vd[r]) + po * bf2f(vo[r])) * inv);
          *(u16x4*)(ob + mf * 16 + g * 4) = pk;
        }
      }
    }
  }
}

// ---------------- merge the four ctx column-slice partials (log2-domain) ----
__global__ __launch_bounds__(256) void merge_k(const ushort* __restrict__ part01,
                                               const ushort* __restrict__ part2,
                                               const ushort* __restrict__ part3a,
                                               ushort* __restrict__ attn_out)
{
  const int task = blockIdx.x * 4 + (threadIdx.x >> 6);   // 0..24767 = h*2064+qrow
  const int lane = threadIdx.x & 63;
  const int h = task / NCTX, qrow = task - h * NCTX;
  const ushort* p0 = part01 + (size_t)(task * 2) * 72;
  const ushort* p1 = p0 + 72;
  const ushort* p2 = part2 + (size_t)task * 72;
  const ushort* p3 = (task < P3SPLIT) ? part3a + (size_t)task * 72
                                      : part01 + 3566592 + (size_t)(task - P3SPLIT) * 72;
  const float* f0 = (const float*)(p0 + 64);
  const float* f1 = (const float*)(p1 + 64);
  const float* f2 = (const float*)(p2 + 64);
  const float* f3 = (const float*)(p3 + 64);
  float m0 = f0[0], l0 = f0[1], m1 = f1[0], l1 = f1[1];
  float m2 = f2[0], l2 = f2[1], m3 = f3[0], l3 = f3[1];
  float M = fmaxf(fmaxf(m0, m1), fmaxf(m2, m3));
  float c0 = ex2(m0 - M), c1 = ex2(m1 - M), c2 = ex2(m2 - M), c3 = ex2(m3 - M);
  float inv = 1.0f / (c0 * l0 + c1 * l1 + c2 * l2 + c3 * l3);
  float v = (c0 * bf2f(p0[lane]) + c1 * bf2f(p1[lane]) +
             c2 * bf2f(p2[lane]) + c3 * bf2f(p3[lane])) * inv;
  attn_out[(size_t)qrow * 768 + h * 64 + lane] = f2bf(v);
}

// ---------------------------------------------------------------------------
extern "C" void kernel_launch(void* const* d_in, const int* in_sizes, int n_in,
                              void* d_out, int out_size, void* d_ws, size_t ws_size,
                              hipStream_t stream)
{
  const float* x       = (const float*)d_in[0];
  const int*   patch_i = (const int*)d_in[1];
  const int*   point_i = (const int*)d_in[2];
  const float* ln1w    = (const float*)d_in[3];
  const float* ln1b    = (const float*)d_in[4];
  const float* qkvw    = (const float*)d_in[5];
  const float* projw   = (const float*)d_in[6];
  const float* projb   = (const float*)d_in[7];
  const float* ln2w    = (const float*)d_in[8];
  const float* ln2b    = (const float*)d_in[9];
  const float* fc1w    = (const float*)d_in[10];
  const float* fc1b    = (const float*)d_in[11];
  const float* fc2w    = (const float*)d_in[12];
  const float* fc2b    = (const float*)d_in[13];

  char* ws = (char*)d_ws;
  ushort* wqkv = (ushort*)(ws + 0);           // 2304x768 bf16; DEAD after qkv
                                              //   GEMM -> reused as part3a
  ushort* wproj = (ushort*)(ws + 3538944);    // 768x768
  ushort* wfc1 = (ushort*)(ws + 4718592);     // 3072x768
  ushort* wfc2 = (ushort*)(ws + 9437184);     // 768x3072
  ushort* xn   = (ushort*)(ws + 14155776);    // ln out bf16 [3088][768]
  ushort* q    = (ushort*)(ws + 18898944);    // [12][3088][64]
  ushort* k    = (ushort*)(ws + 23642112);
  ushort* v    = (ushort*)(ws + 28385280);
  ushort* vt   = (ushort*)(ws + 33128448);    // [12][64][3088]
  ushort* attn = (ushort*)(ws + 37871616);    // [3088][768] bf16
  float*  x1   = (float*)(ws + 42614784);     // [3088][768] fp32
  ushort* part01 = (ushort*)(ws + 42614784);  // ctx partials slices 0,1 (7.13MB)
                                              //   + slice-3 tail (27.6KB);
                                              //   dead before x1 written (proj)
  ushort* part2  = xn;                        // slice 2: xn dead between
                                              //   qkv-GEMM and ln_k
  ushort* part3a = wqkv;                      // slice 3 (tasks<24576): wqkv
                                              //   dead after qkv-GEMM, 3.54MB
  int*    pmm  = (int*)(ws + 52101120);       // lo16,hi16,qoff16,qcnt16,qidx1024
  ushort* h1   = q;                           // fc1 out reuses q..vt
  ushort* h2n  = xn;

  prep<<<1728 + 3088 + 1, 256, 0, stream>>>(qkvw, wqkv, x, ln1w, ln1b, xn,
                                            patch_i, point_i, pmm);
  gemmk<0, 128, 128, 1><<<dim3(18, 25), 256, 0, stream>>>(xn, wqkv, 768, q, k, v, vt,
                                                          nullptr, nullptr, nullptr, nullptr);
  attn_fused<<<NCTXB + 192 * QCH + 5184, 256, 0, stream>>>(q, k, v, vt, pmm,
                                                           part01, part2, part3a, attn,
                                                           projw, fc1w, fc2w,
                                                           wproj, wfc1, wfc2);
  merge_k<<<6192, 256, 0, stream>>>(part01, part2, part3a, attn);
  gemm64<1, 1><<<dim3(12, 49), 256, 0, stream>>>(attn, wproj, 768, x1, projb, x);
  ln_k<<<3088, 256, 0, stream>>>(x1, ln2w, ln2b, h2n, fc2b, (float*)d_out);
  gemmk<2, 128, 128, 1><<<dim3(24, 25), 256, 0, stream>>>(h2n, wfc1, 768, nullptr, nullptr,
                                                          nullptr, nullptr, nullptr, fc1b, nullptr, h1);
  gemm64<4, 2><<<dim3(12, 98), 256, 0, stream>>>(h1, wfc2, 3072, (float*)d_out, nullptr, nullptr);
}

// Round 25
// 170.628 us; speedup vs baseline: 1.0115x; 1.0115x over previous
//
#include <hip/hip_runtime.h>
#include <math.h>

typedef __attribute__((ext_vector_type(8))) short bf16x8;   // 8 bf16 (4 VGPRs)
typedef __attribute__((ext_vector_type(4))) float f32x4;    // MFMA C/D frag
typedef __attribute__((ext_vector_type(4))) unsigned short u16x4;
typedef __attribute__((ext_vector_type(8))) unsigned short u16x8;

#define MROWS 3088      // N tokens
#define NCTX  2064      // context rows/cols (N - Q)
#define NQ    1024
#define HEADS 12
#define QCH   16        // max 64-row chunks per object (robustness)
#define NCTXB 1188      // ctx blocks: 33 qt x 12 h x 3 column-thirds
#define SC2   0.1803368801111f   // 0.125 * log2(e): softmax in base-2 domain

__device__ __forceinline__ ushort f2bf(float f){
  union { float f; unsigned u; } c; c.f = f;
  unsigned r = c.u + 0x7fffu + ((c.u >> 16) & 1u);   // RNE
  return (ushort)(r >> 16);
}
__device__ __forceinline__ float bf2f(ushort u){
  union { unsigned u; float f; } c; c.u = ((unsigned)u) << 16;
  return c.f;
}
__device__ __forceinline__ float ex2(float x){ return __builtin_amdgcn_exp2f(x); }
__device__ __forceinline__ unsigned cvtpk(float lo, float hi){
  unsigned r;
  asm("v_cvt_pk_bf16_f32 %0, %1, %2" : "=v"(r) : "v"(lo), "v"(hi));
  return r;
}
__device__ __forceinline__ float gelu_f(float x){
  return 0.5f * x * (1.0f + erff(x * 0.7071067811865475f));
}
__device__ __forceinline__ void gll16(const ushort* src, char* ldsdst){
  __builtin_amdgcn_global_load_lds((const __attribute__((address_space(1))) void*)src,
                                   (__attribute__((address_space(3))) void*)ldsdst, 16, 0, 0);
}

// ---------------- prep: wconv(qkv only) + ln1 + seg_minmax + bucketing ------
__global__ __launch_bounds__(256) void prep(
    const float* __restrict__ w0, ushort* __restrict__ o0,
    const float* __restrict__ x, const float* __restrict__ lnw,
    const float* __restrict__ lnb, ushort* __restrict__ xn,
    const int* __restrict__ patch_idx, const int* __restrict__ point_idx,
    int* __restrict__ pmm)
{
  const int b = blockIdx.x;
  const int t = threadIdx.x;
  if (b < 1728) {                              // ---- qkv weight convert
    int c = b * 256 + t;                       // c < 442368
    f32x4 v = *(const f32x4*)(w0 + (size_t)c * 4);
    u16x4 r;
    r[0] = f2bf(v[0]); r[1] = f2bf(v[1]); r[2] = f2bf(v[2]); r[3] = f2bf(v[3]);
    *(u16x4*)(o0 + (size_t)c * 4) = r;
  } else if (b < 1728 + 3088) {                // ---- layernorm 1
    int row = b - 1728;
    const float* xr = x + (size_t)row * 768;
    float v0 = xr[t], v1 = xr[t + 256], v2 = xr[t + 512];
    float s = v0 + v1 + v2;
    float ss = v0 * v0 + v1 * v1 + v2 * v2;
#pragma unroll
    for (int o = 32; o >= 1; o >>= 1) { s += __shfl_xor(s, o); ss += __shfl_xor(ss, o); }
    __shared__ float red[8];
    int wv = t >> 6;
    if ((t & 63) == 0) { red[wv] = s; red[4 + wv] = ss; }
    __syncthreads();
    s = red[0] + red[1] + red[2] + red[3];
    ss = red[4] + red[5] + red[6] + red[7];
    float mean = s * (1.0f / 768.0f);
    float var = ss * (1.0f / 768.0f) - mean * mean;
    float rstd = rsqrtf(var + 1e-5f);
    ushort* orow = xn + (size_t)row * 768;
    orow[t]       = f2bf((v0 - mean) * rstd * lnw[t]       + lnb[t]);
    orow[t + 256] = f2bf((v1 - mean) * rstd * lnw[t + 256] + lnb[t + 256]);
    orow[t + 512] = f2bf((v2 - mean) * rstd * lnw[t + 512] + lnb[t + 512]);
  } else {                                     // ---- seg min/max + bucketing
    __shared__ int smin[16], smax[16], hcnt[16], hoff[16], hcur[16];
    if (t < 16) { smin[t] = 0x7fffffff; smax[t] = -1; hcnt[t] = 0; }
    __syncthreads();
    for (int i = t; i < 2048; i += 256) {
      int o = patch_idx[i];
      atomicMin(&smin[o], i);
      atomicMax(&smax[o], i);
    }
    for (int i = t; i < 1024; i += 256)
      atomicAdd(&hcnt[point_idx[i]], 1);
    __syncthreads();
    if (t == 0) {
      int acc = 0;
      for (int o = 0; o < 16; o++) { hoff[o] = acc; hcur[o] = acc; acc += hcnt[o]; }
    }
    __syncthreads();
    for (int i = t; i < 1024; i += 256) {
      int o = point_idx[i];
      int p = atomicAdd(&hcur[o], 1);
      pmm[64 + p] = i;                         // qidx
    }
    if (t < 16) {
      pmm[t]      = (smin[t] == 0x7fffffff) ? (1 << 30) : smin[t] + 16;  // lo
      pmm[16 + t] = smax[t] + 16;                                        // hi
      pmm[32 + t] = hoff[t];                                             // qoff
      pmm[48 + t] = hcnt[t];                                             // qcnt
    }
  }
}

// ---------------- layernorm + d_out init (x1 + fc2 bias) --------------------
__global__ __launch_bounds__(256) void ln_k(const float* __restrict__ x,
                                            const float* __restrict__ w,
                                            const float* __restrict__ b,
                                            ushort* __restrict__ out,
                                            const float* __restrict__ fc2b,
                                            float* __restrict__ dinit)
{
  int row = blockIdx.x, t = threadIdx.x;
  const float* xr = x + (size_t)row * 768;
  float v0 = xr[t], v1 = xr[t + 256], v2 = xr[t + 512];
  float s = v0 + v1 + v2;
  float ss = v0 * v0 + v1 * v1 + v2 * v2;
#pragma unroll
  for (int o = 32; o >= 1; o >>= 1) { s += __shfl_xor(s, o); ss += __shfl_xor(ss, o); }
  __shared__ float red[8];
  int wv = t >> 6;
  if ((t & 63) == 0) { red[wv] = s; red[4 + wv] = ss; }
  __syncthreads();
  s = red[0] + red[1] + red[2] + red[3];
  ss = red[4] + red[5] + red[6] + red[7];
  float mean = s * (1.0f / 768.0f);
  float var = ss * (1.0f / 768.0f) - mean * mean;
  float rstd = rsqrtf(var + 1e-5f);
  ushort* orow = out + (size_t)row * 768;
  orow[t]       = f2bf((v0 - mean) * rstd * w[t]       + b[t]);
  orow[t + 256] = f2bf((v1 - mean) * rstd * w[t + 256] + b[t + 256]);
  orow[t + 512] = f2bf((v2 - mean) * rstd * w[t + 512] + b[t + 512]);
  float* drow = dinit + (size_t)row * 768;     // fc2 split-K accumulator base
  drow[t]       = v0 + fc2b[t];
  drow[t + 256] = v1 + fc2b[t + 256];
  drow[t + 512] = v2 + fc2b[t + 512];
}

// ---------------- MFMA GEMM 128x128, BK=32 (qkv, fc1) -----------------------
// MODE 0: qkv scatter -> q/k/v [12][3088][64] bf16 + vT [12][64][3088] bf16
// MODE 2: bf16 out = gelu(acc + bias[col])                  (stride 3072)
template<int MODE, int BM, int BN, int KSPLIT>
__global__ __launch_bounds__(256, 2) void gemmk(
    const ushort* __restrict__ A, const ushort* __restrict__ Bw, int K,
    ushort* __restrict__ oq, ushort* __restrict__ ok,
    ushort* __restrict__ ov, ushort* __restrict__ ovt,
    float* __restrict__ of, const float* __restrict__ bias,
    const float* __restrict__ resid, ushort* __restrict__ oh)
{
  constexpr int MF = (BM == 64 && BN == 64) ? 2 : 4;
  constexpr int NF = (BM == 128 && BN == 128) ? 4 : 2;
  constexpr int GLLS = BM / 64 + BN / 64;      // gll per thread per stage
  constexpr int ABUF = BM * 64;                // bytes per A buffer
  constexpr int BBUF = BN * 64;
  __shared__ ushort ldsA[3 * BM * 32];
  __shared__ ushort ldsB[3 * BN * 32];
  const int tid = threadIdx.x;
  const int lane = tid & 63;
  const int wv = tid >> 6;
  const int g = lane >> 4, lq = lane & 15;

  // XCD swizzle: hw linear d -> logical l (x-major), chunked per XCD
  const int nwg = gridDim.x * gridDim.y;
  const int d = blockIdx.y * gridDim.x + blockIdx.x;
  const int qq = nwg >> 3, rr = nwg & 7, xcd = d & 7, ii = d >> 3;
  const int l = (xcd < rr ? xcd * (qq + 1) : rr * (qq + 1) + (xcd - rr) * qq) + ii;
  const int bx = l % gridDim.x, byl = l / gridDim.x;

  const int ybl = gridDim.y / KSPLIT;
  const int ks = (KSPLIT == 2) ? (byl / ybl) : 0;
  const int by = byl - ks * ybl;
  const int k0 = ks * (K / KSPLIT);
  const int klen = K / KSPLIT;

  const int row0 = by * BM, col0 = bx * BN;
  const int wrow = (BM == 128) ? (wv >> 1) * 64 : ((BN == 64) ? (wv >> 1) * 32 : 0);
  const int wcol = (BM == 128) ? (wv & 1) * 64 : ((BN == 64) ? (wv & 1) * 32 : wv * 32);

  f32x4 acc[MF][NF] = {};

  const int rS = tid >> 2;
  const int cS = (tid & 3) ^ ((rS >> 1) & 3);
  int arow0 = row0 + rS;       if (arow0 > MROWS - 1) arow0 = MROWS - 1;
  int arow1 = row0 + 64 + rS;  if (arow1 > MROWS - 1) arow1 = MROWS - 1;
  const ushort* srcA0 = A + (size_t)arow0 * K + k0 + cS * 8;
  const ushort* srcA1 = A + (size_t)arow1 * K + k0 + cS * 8;   // BM==128 only
  const ushort* srcB0 = Bw + (size_t)(col0 + rS) * K + k0 + cS * 8;
  const ushort* srcB1 = Bw + (size_t)(col0 + 64 + rS) * K + k0 + cS * 8;

  auto STAGE = [&](int kk, int buf) {
    char* ab = (char*)ldsA + buf * ABUF + wv * 1024;
    char* bb = (char*)ldsB + buf * BBUF + wv * 1024;
    gll16(srcA0 + kk, ab);
    if constexpr (BM == 128) gll16(srcA1 + kk, ab + 4096);
    gll16(srcB0 + kk, bb);
    if constexpr (BN == 128) gll16(srcB1 + kk, bb + 4096);
  };

  const int nIter = klen >> 5;
  STAGE(0, 0);
  STAGE(32, 1);
  int bufc = 0;
  for (int t = 0; t < nIter; t++) {
    if (t + 2 < nIter) {
      int bn = bufc + 2; if (bn >= 3) bn -= 3;
      STAGE((t + 2) << 5, bn);
      asm volatile("s_waitcnt vmcnt(%0)" :: "i"(2 * GLLS) : "memory");
    } else if (t + 1 < nIter) {
      asm volatile("s_waitcnt vmcnt(%0)" :: "i"(GLLS) : "memory");
    } else {
      asm volatile("s_waitcnt vmcnt(0)" ::: "memory");
    }
    __builtin_amdgcn_s_barrier();

    const char* pa = (char*)ldsA + bufc * ABUF;
    const char* pb = (char*)ldsB + bufc * BBUF;
    bf16x8 af[MF], bfr[NF];
#pragma unroll
    for (int mf = 0; mf < MF; mf++) {
      int r = wrow + mf * 16 + lq;
      af[mf] = *(const bf16x8*)(pa + r * 64 + ((g ^ ((r >> 1) & 3)) << 4));
    }
#pragma unroll
    for (int nf = 0; nf < NF; nf++) {
      int c = wcol + nf * 16 + lq;
      bfr[nf] = *(const bf16x8*)(pb + c * 64 + ((g ^ ((c >> 1) & 3)) << 4));
    }
#pragma unroll
    for (int mf = 0; mf < MF; mf++)
#pragma unroll
      for (int nf = 0; nf < NF; nf++)
        acc[mf][nf] = __builtin_amdgcn_mfma_f32_16x16x32_bf16(af[mf], bfr[nf], acc[mf][nf], 0, 0, 0);
    __builtin_amdgcn_s_barrier();
    bufc++; if (bufc >= 3) bufc = 0;
  }

  // epilogue: C frag layout col = lane&15, row = (lane>>4)*4 + reg   [m89]
#pragma unroll
  for (int mf = 0; mf < MF; mf++) {
    int rowb = row0 + wrow + mf * 16 + g * 4;
    if (rowb >= MROWS) continue;
#pragma unroll
    for (int nf = 0; nf < NF; nf++) {
      int col = col0 + wcol + nf * 16 + lq;
      if (MODE == 0) {
        int which = col / 768;
        int rem = col - which * 768;
        int hd = rem >> 6, dd = rem & 63;
        size_t base = ((size_t)hd * MROWS + rowb) * 64 + dd;
        ushort b0 = f2bf(acc[mf][nf][0]);
        ushort b1 = f2bf(acc[mf][nf][1]);
        ushort b2 = f2bf(acc[mf][nf][2]);
        ushort b3 = f2bf(acc[mf][nf][3]);
        ushort* dst = (which == 0) ? oq : (which == 1) ? ok : ov;
        dst[base] = b0; dst[base + 64] = b1; dst[base + 128] = b2; dst[base + 192] = b3;
        if (which == 2) {
          u16x4 pk; pk[0] = b0; pk[1] = b1; pk[2] = b2; pk[3] = b3;
          *(u16x4*)&ovt[((size_t)hd * 64 + dd) * MROWS + rowb] = pk;   // V^T
        }
      } else if (MODE == 1) {
#pragma unroll
        for (int r = 0; r < 4; r++) {
          size_t idx = (size_t)(rowb + r) * 768 + col;
          of[idx] = acc[mf][nf][r] + bias[col] + resid[idx];
        }
      } else {
#pragma unroll
        for (int r = 0; r < 4; r++) {
          size_t idx = (size_t)(rowb + r) * 3072 + col;
          oh[idx] = f2bf(gelu_f(acc[mf][nf][r] + bias[col]));
        }
      }
    }
  }
}

// ---------------- MFMA GEMM 64x64, BK=64 (proj, fc2) ------------------------
// Triple-buffered (prefetch depth 2), 2 barriers/iter — BEST MEASURED (R16).
// KSPLIT=2 pairs the two K-halves of an output tile on ADJACENT logical ids
// (ks = byl&1, same XCD): second atomicAdd hits that XCD's L2.
// MODE 1: fp32 out = acc+bias+resid. MODE 4: atomicAdd fp32 (init preloaded).
template<int MODE, int KSPLIT>
__global__ __launch_bounds__(256, 2) void gemm64(
    const ushort* __restrict__ A, const ushort* __restrict__ Bw, int K,
    float* __restrict__ of, const float* __restrict__ bias,
    const float* __restrict__ resid)
{
  __shared__ ushort ldsA[3 * 64 * 64];         // 24 KB
  __shared__ ushort ldsB[3 * 64 * 64];         // 24 KB
  const int tid = threadIdx.x;
  const int lane = tid & 63;
  const int wv = tid >> 6;
  const int g = lane >> 4, lq = lane & 15;

  // XCD swizzle (bijective, m204)
  const int nwg = gridDim.x * gridDim.y;
  const int d = blockIdx.y * gridDim.x + blockIdx.x;
  const int qq = nwg >> 3, rr = nwg & 7, xcd = d & 7, ii = d >> 3;
  const int l = (xcd < rr ? xcd * (qq + 1) : rr * (qq + 1) + (xcd - rr) * qq) + ii;
  const int bx = l % gridDim.x, byl = l / gridDim.x;
  const int ks = (KSPLIT > 1) ? (byl & (KSPLIT - 1)) : 0;    // K-slices adjacent
  const int by = (KSPLIT > 1) ? (byl / KSPLIT) : byl;
  const int k0 = ks * (K / KSPLIT);
  const int klen = K / KSPLIT;

  const int row0 = by * 64, col0 = bx * 64;
  const int wrow = (wv >> 1) * 32, wcol = (wv & 1) * 32;

  f32x4 acc[2][2] = {};

  const int rA0 = tid >> 3;
  const int cL  = (tid & 7) ^ (rA0 & 7);       // same for rA0+32 (32 = 0 mod 8)
  int ar0 = row0 + rA0;       if (ar0 > MROWS - 1) ar0 = MROWS - 1;
  int ar1 = row0 + rA0 + 32;  if (ar1 > MROWS - 1) ar1 = MROWS - 1;
  const ushort* sA0 = A + (size_t)ar0 * K + k0 + cL * 8;
  const ushort* sA1 = A + (size_t)ar1 * K + k0 + cL * 8;
  const ushort* sB0 = Bw + (size_t)(col0 + rA0) * K + k0 + cL * 8;
  const ushort* sB1 = Bw + (size_t)(col0 + rA0 + 32) * K + k0 + cL * 8;

  auto STAGE = [&](int kk, int buf) {
    char* ab = (char*)ldsA + buf * 8192 + wv * 1024;
    char* bb = (char*)ldsB + buf * 8192 + wv * 1024;
    gll16(sA0 + kk, ab);
    gll16(sA1 + kk, ab + 4096);
    gll16(sB0 + kk, bb);
    gll16(sB1 + kk, bb + 4096);
  };

  const int nIter = klen >> 6;
  STAGE(0, 0);
  STAGE(64, 1);
  int bufc = 0;
  for (int t = 0; t < nIter; t++) {
    if (t + 2 < nIter) {
      int bn = bufc + 2; if (bn >= 3) bn -= 3;
      STAGE((t + 2) << 6, bn);
      asm volatile("s_waitcnt vmcnt(8)" ::: "memory");
    } else if (t + 1 < nIter) {
      asm volatile("s_waitcnt vmcnt(4)" ::: "memory");
    } else {
      asm volatile("s_waitcnt vmcnt(0)" ::: "memory");
    }
    __builtin_amdgcn_s_barrier();

    const char* pa = (char*)ldsA + bufc * 8192;
    const char* pb = (char*)ldsB + bufc * 8192;
    bf16x8 af[2][2], bfr[2][2];
#pragma unroll
    for (int mf = 0; mf < 2; mf++) {
      int r = wrow + mf * 16 + lq;
#pragma unroll
      for (int k2 = 0; k2 < 2; k2++)
        af[mf][k2] = *(const bf16x8*)(pa + r * 128 + ((((k2 << 2) + g) ^ (r & 7)) << 4));
    }
#pragma unroll
    for (int nf = 0; nf < 2; nf++) {
      int c = wcol + nf * 16 + lq;
#pragma unroll
      for (int k2 = 0; k2 < 2; k2++)
        bfr[nf][k2] = *(const bf16x8*)(pb + c * 128 + ((((k2 << 2) + g) ^ (c & 7)) << 4));
    }
#pragma unroll
    for (int mf = 0; mf < 2; mf++)
#pragma unroll
      for (int nf = 0; nf < 2; nf++) {
        acc[mf][nf] = __builtin_amdgcn_mfma_f32_16x16x32_bf16(af[mf][0], bfr[nf][0], acc[mf][nf], 0, 0, 0);
        acc[mf][nf] = __builtin_amdgcn_mfma_f32_16x16x32_bf16(af[mf][1], bfr[nf][1], acc[mf][nf], 0, 0, 0);
      }
    __builtin_amdgcn_s_barrier();
    bufc++; if (bufc >= 3) bufc = 0;
  }

  // epilogue: C frag layout col = lane&15, row = (lane>>4)*4 + reg   [m89]
#pragma unroll
  for (int mf = 0; mf < 2; mf++) {
    int rowb = row0 + wrow + mf * 16 + g * 4;
    if (rowb >= MROWS) continue;
#pragma unroll
    for (int nf = 0; nf < 2; nf++) {
      int col = col0 + wcol + nf * 16 + lq;
      if (MODE == 1) {
#pragma unroll
        for (int r = 0; r < 4; r++) {
          size_t idx = (size_t)(rowb + r) * 768 + col;
          of[idx] = acc[mf][nf][r] + bias[col] + resid[idx];
        }
      } else {
#pragma unroll
        for (int r = 0; r < 4; r++) {
          size_t idx = (size_t)(rowb + r) * 768 + col;
          atomicAdd(&of[idx], acc[mf][nf][r]);
        }
      }
    }
  }
}

// ---------------- fused attention (+ wconv tail for proj/fc1/fc2) -----------
// ctx: 3-way COLUMN split — block (qt,h,third) does tiles [third*11,+11),
// partials for third 0,1 -> part01; third 2 -> part2 (dead xn region).
// Softmax in BASE-2 domain (SC2 pre-scale, raw v_exp_f32, m/l in log2).
__global__ __launch_bounds__(256) void attn_fused(
    const ushort* __restrict__ qarr, const ushort* __restrict__ karr,
    const ushort* __restrict__ varr, const ushort* __restrict__ vt,
    const int* __restrict__ pmm, ushort* __restrict__ part01,
    ushort* __restrict__ part2, ushort* __restrict__ attn_out,
    const float* __restrict__ cw1, const float* __restrict__ cw2,
    const float* __restrict__ cw3, ushort* __restrict__ cd1,
    ushort* __restrict__ cd2, ushort* __restrict__ cd3)
{
  __shared__ ushort ldsK[2][64 * 64];
  __shared__ ushort ldsV[2][64 * 64];
  const int tid = threadIdx.x;
  const int lane = tid & 63;
  const int wv = tid >> 6;
  const int b = blockIdx.x;
  const int g = lane >> 4, lq = lane & 15;

  if (b >= NCTXB + 3072) {                     // ============ weight convert
    int c = 442368 + (b - NCTXB - 3072) * 256 + tid;
    const float* src; ushort* dst; int i;
    if (c < 589824)       { src = cw1; dst = cd1; i = c - 442368; }   // proj
    else if (c < 1179648) { src = cw2; dst = cd2; i = c - 589824; }   // fc1
    else                  { src = cw3; dst = cd3; i = c - 1179648; }  // fc2
    f32x4 v = *(const f32x4*)(src + (size_t)i * 4);
    u16x4 r;
    r[0] = f2bf(v[0]); r[1] = f2bf(v[1]); r[2] = f2bf(v[2]); r[3] = f2bf(v[3]);
    *(u16x4*)(dst + (size_t)i * 4) = r;
    return;
  }

  // common staging geometry
  const int n0 = tid, n1 = 256 + tid;
  const int r0s = n0 >> 3, c0s = (n0 & 7) ^ (r0s & 3) ^ (((r0s >> 3) & 1) << 2);
  const int r1s = n1 >> 3, c1s = (n1 & 7) ^ (r1s & 3) ^ (((r1s >> 3) & 1) << 2);
  char* dk0 = (char*)&ldsK[0][0] + wv * 1024;
  char* dv0 = (char*)&ldsV[0][0] + wv * 1024;

  auto ldK = [&](int buf, int r, int c) -> bf16x8 {
    int cs = c ^ (r & 3) ^ (((r >> 3) & 1) << 2);
    return *(const bf16x8*)&ldsK[buf][r * 64 + cs * 8];
  };
  auto ldV = [&](int buf, int r, int c) -> bf16x8 {
    int cs = c ^ (r & 3) ^ (((r >> 3) & 1) << 2);
    return *(const bf16x8*)&ldsV[buf][r * 64 + cs * 8];
  };
  const int kfr0 = (lq >> 2) * 8 + (lq & 3);   // A-frag row perm

  if (b < NCTXB) {                             // ================= context
    // bijective XCD swizzle over 1188 blocks (q=148, r=4);
    // logical l = h*99 + qt*3 + third
    const int xcd = b & 7, ii = b >> 3;
    const int l = (xcd < 4 ? xcd * 149 : 4 * 149 + (xcd - 4) * 148) + ii;
    const int h = l / 99;
    const int rem = l - h * 99;
    const int qt = rem / 3, third = rem - qt * 3;
    const int qrow = qt * 64 + wv * 16 + lq;
    const int qload = qrow < NCTX ? qrow : NCTX - 1;
    const size_t hb = (size_t)h * MROWS;

    const ushort* qb = qarr + (hb + qload) * 64 + g * 8;
    bf16x8 qf0 = *(const bf16x8*)qb;
    bf16x8 qf1 = *(const bf16x8*)(qb + 32);

    auto STAGE = [&](int t, int buf) {
      int cb = t * 64;
      int kr0 = cb + r0s; if (kr0 > NCTX - 1) kr0 = NCTX - 1;
      int kr1 = cb + r1s; if (kr1 > NCTX - 1) kr1 = NCTX - 1;
      char* dk = dk0 + buf * 8192;
      char* dv = dv0 + buf * 8192;
      gll16(karr + (hb + kr0) * 64 + c0s * 8, dk);
      gll16(karr + (hb + kr1) * 64 + c1s * 8, dk + 4096);
      gll16(vt + ((size_t)h * 64 + r0s) * MROWS + cb + c0s * 8, dv);
      gll16(vt + ((size_t)h * 64 + r1s) * MROWS + cb + c1s * 8, dv + 4096);
    };

    float m = -1e30f, lsum = 0.0f;
    f32x4 o[4] = {};

    const int t0 = third * 11;
    const int nt = 11;                         // 33 = 3 x 11 tiles
    STAGE(t0, 0);
    for (int ti = 0; ti < nt; ti++) {
      const int t = t0 + ti;
      const int cur = ti & 1;
      if (ti + 1 < nt) {
        STAGE(t + 1, cur ^ 1);
        asm volatile("s_waitcnt vmcnt(4)" ::: "memory");
      } else {
        asm volatile("s_waitcnt vmcnt(0)" ::: "memory");
      }
      __builtin_amdgcn_s_barrier();

      const int cb = t * 64;
      float s[16];
#pragma unroll
      for (int hf = 0; hf < 2; hf++) {
        int rb = hf * 32 + kfr0;
        bf16x8 ka00 = ldK(cur, rb, g);
        bf16x8 ka01 = ldK(cur, rb, g + 4);
        bf16x8 ka10 = ldK(cur, rb + 4, g);
        bf16x8 ka11 = ldK(cur, rb + 4, g + 4);
        f32x4 st0 = {0.f, 0.f, 0.f, 0.f}, st1 = {0.f, 0.f, 0.f, 0.f};
        st0 = __builtin_amdgcn_mfma_f32_16x16x32_bf16(ka00, qf0, st0, 0, 0, 0);
        st0 = __builtin_amdgcn_mfma_f32_16x16x32_bf16(ka01, qf1, st0, 0, 0, 0);
        st1 = __builtin_amdgcn_mfma_f32_16x16x32_bf16(ka10, qf0, st1, 0, 0, 0);
        st1 = __builtin_amdgcn_mfma_f32_16x16x32_bf16(ka11, qf1, st1, 0, 0, 0);
#pragma unroll
        for (int r = 0; r < 4; r++) {
          s[hf * 8 + r] = st0[r] * SC2;
          s[hf * 8 + 4 + r] = st1[r] * SC2;
        }
      }
      if (cb + 64 > NCTX) {
#pragma unroll
        for (int hf = 0; hf < 2; hf++)
          if (cb + hf * 32 + g * 8 >= NCTX) {
#pragma unroll
            for (int j = 0; j < 8; j++) s[hf * 8 + j] = -1e30f;
          }
      }
      float tm = s[0];
#pragma unroll
      for (int j = 1; j < 16; j++) tm = fmaxf(tm, s[j]);
      tm = fmaxf(tm, __shfl_xor(tm, 16));
      tm = fmaxf(tm, __shfl_xor(tm, 32));
      float nm = fmaxf(m, tm);
      bool resc = !__all(tm <= m);             // skip rescale if max unchanged
      float p[16], ps = 0.f;
#pragma unroll
      for (int j = 0; j < 16; j++) { p[j] = ex2(s[j] - nm); ps += p[j]; }
      ps += __shfl_xor(ps, 16);
      ps += __shfl_xor(ps, 32);
      if (resc) {
        float alpha = ex2(m - nm);
        lsum = lsum * alpha;
#pragma unroll
        for (int mf = 0; mf < 4; mf++) {
          o[mf][0] *= alpha; o[mf][1] *= alpha; o[mf][2] *= alpha; o[mf][3] *= alpha;
        }
      }
      lsum += ps;
      m = nm;
#pragma unroll
      for (int hf = 0; hf < 2; hf++) {
        union { bf16x8 v; unsigned u[4]; } pb;
        pb.u[0] = cvtpk(p[hf * 8 + 0], p[hf * 8 + 1]);
        pb.u[1] = cvtpk(p[hf * 8 + 2], p[hf * 8 + 3]);
        pb.u[2] = cvtpk(p[hf * 8 + 4], p[hf * 8 + 5]);
        pb.u[3] = cvtpk(p[hf * 8 + 6], p[hf * 8 + 7]);
#pragma unroll
        for (int mf = 0; mf < 4; mf++) {
          bf16x8 va = ldV(cur, mf * 16 + lq, hf * 4 + g);
          o[mf] = __builtin_amdgcn_mfma_f32_16x16x32_bf16(va, pb.v, o[mf], 0, 0, 0);
        }
      }
      __builtin_amdgcn_s_barrier();
    }

    if (qrow < NCTX) {                         // write partial (o bf16, m, l)
      const int task = h * NCTX + qrow;
      ushort* pe = (third < 2) ? part01 + (size_t)((task << 1) + third) * 72
                               : part2 + (size_t)task * 72;
#pragma unroll
      for (int mf = 0; mf < 4; mf++) {
        u16x4 pk;
        pk[0] = f2bf(o[mf][0]); pk[1] = f2bf(o[mf][1]);
        pk[2] = f2bf(o[mf][2]); pk[3] = f2bf(o[mf][3]);
        *(u16x4*)(pe + mf * 16 + g * 4) = pk;
      }
      if (g == 0) {
        float* fl = (float*)(pe + 64);
        fl[0] = m; fl[1] = lsum;               // m in log2 domain
      }
    }
  } else {                                     // ============ grouped queries
    const int idx = b - NCTXB;
    const int ch = idx / 192;                  // chunk-major: active blocks first
    const int oh = idx % 192;
    const int obj = oh & 15, h = oh >> 4;
    const int cnt = pmm[48 + obj];
    if (ch * 64 >= cnt) return;
    const int lo = pmm[obj], hi = pmm[16 + obj];
    const int qoff = pmm[32 + obj];
    const size_t hb = (size_t)h * MROWS;

    const int ridx = ch * 64 + wv * 16 + lq;
    const bool rvalid = ridx < cnt;
    const int qi = rvalid ? pmm[64 + qoff + ridx] : 0;
    const int grow = NCTX + qi;                // global token row

    const ushort* qb = qarr + (hb + grow) * 64 + g * 8;
    bf16x8 qf0 = *(const bf16x8*)qb;
    bf16x8 qf1 = *(const bf16x8*)(qb + 32);

    const int lo8 = lo & ~7;                   // 16B-align the column window
    const int ntiles = (hi - lo8 + 64) >> 6;   // covers [lo8, hi]

    auto STAGE = [&](int t, int buf) {
      int cb = lo8 + t * 64;
      int kr0 = cb + r0s; if (kr0 > MROWS - 1) kr0 = MROWS - 1;
      int kr1 = cb + r1s; if (kr1 > MROWS - 1) kr1 = MROWS - 1;
      char* dk = dk0 + buf * 8192;
      char* dv = dv0 + buf * 8192;
      gll16(karr + (hb + kr0) * 64 + c0s * 8, dk);
      gll16(karr + (hb + kr1) * 64 + c1s * 8, dk + 4096);
      gll16(vt + ((size_t)h * 64 + r0s) * MROWS + cb + c0s * 8, dv);
      gll16(vt + ((size_t)h * 64 + r1s) * MROWS + cb + c1s * 8, dv + 4096);
    };

    float m = -1e30f, lsum = 0.0f;
    f32x4 o[4] = {};

    STAGE(0, 0);
    for (int t = 0; t < ntiles; t++) {
      const int cur = t & 1;
      if (t + 1 < ntiles) {
        STAGE(t + 1, cur ^ 1);
        asm volatile("s_waitcnt vmcnt(4)" ::: "memory");
      } else {
        asm volatile("s_waitcnt vmcnt(0)" ::: "memory");
      }
      __builtin_amdgcn_s_barrier();

      const int cb = lo8 + t * 64;
      float s[16];
#pragma unroll
      for (int hf = 0; hf < 2; hf++) {
        int rb = hf * 32 + kfr0;
        bf16x8 ka00 = ldK(cur, rb, g);
        bf16x8 ka01 = ldK(cur, rb, g + 4);
        bf16x8 ka10 = ldK(cur, rb + 4, g);
        bf16x8 ka11 = ldK(cur, rb + 4, g + 4);
        f32x4 st0 = {0.f, 0.f, 0.f, 0.f}, st1 = {0.f, 0.f, 0.f, 0.f};
        st0 = __builtin_amdgcn_mfma_f32_16x16x32_bf16(ka00, qf0, st0, 0, 0, 0);
        st0 = __builtin_amdgcn_mfma_f32_16x16x32_bf16(ka01, qf1, st0, 0, 0, 0);
        st1 = __builtin_amdgcn_mfma_f32_16x16x32_bf16(ka10, qf0, st1, 0, 0, 0);
        st1 = __builtin_amdgcn_mfma_f32_16x16x32_bf16(ka11, qf1, st1, 0, 0, 0);
        int c0 = cb + hf * 32 + g * 8;
#pragma unroll
        for (int r = 0; r < 4; r++) {
          s[hf * 8 + r]     = (c0 + r >= lo && c0 + r <= hi) ? st0[r] * SC2 : -1e30f;
          s[hf * 8 + 4 + r] = (c0 + 4 + r >= lo && c0 + 4 + r <= hi) ? st1[r] * SC2 : -1e30f;
        }
      }
      float tm = s[0];
#pragma unroll
      for (int j = 1; j < 16; j++) tm = fmaxf(tm, s[j]);
      tm = fmaxf(tm, __shfl_xor(tm, 16));
      tm = fmaxf(tm, __shfl_xor(tm, 32));
      float nm = fmaxf(m, tm);
      bool resc = !__all(tm <= m);
      float p[16], ps = 0.f;
#pragma unroll
      for (int j = 0; j < 16; j++) { p[j] = ex2(s[j] - nm); ps += p[j]; }
      ps += __shfl_xor(ps, 16);
      ps += __shfl_xor(ps, 32);
      if (resc) {
        float alpha = ex2(m - nm);
        lsum = lsum * alpha;
#pragma unroll
        for (int mf = 0; mf < 4; mf++) {
          o[mf][0] *= alpha; o[mf][1] *= alpha; o[mf][2] *= alpha; o[mf][3] *= alpha;
        }
      }
      lsum += ps;
      m = nm;
#pragma unroll
      for (int hf = 0; hf < 2; hf++) {
        union { bf16x8 v; unsigned u[4]; } pb;
        pb.u[0] = cvtpk(p[hf * 8 + 0], p[hf * 8 + 1]);
        pb.u[1] = cvtpk(p[hf * 8 + 2], p[hf * 8 + 3]);
        pb.u[2] = cvtpk(p[hf * 8 + 4], p[hf * 8 + 5]);
        pb.u[3] = cvtpk(p[hf * 8 + 6], p[hf * 8 + 7]);
#pragma unroll
        for (int mf = 0; mf < 4; mf++) {
          bf16x8 va = ldV(cur, mf * 16 + lq, hf * 4 + g);
          o[mf] = __builtin_amdgcn_mfma_f32_16x16x32_bf16(va, pb.v, o[mf], 0, 0, 0);
        }
      }
      __builtin_amdgcn_s_barrier();
    }

    // ---- diag (own token) + object-token columns, merged per-row ----
    {
      const ushort* kd = karr + (hb + grow) * 64 + g * 8;
      const ushort* ko = karr + (hb + obj) * 64 + g * 8;
      bf16x8 kd0 = *(const bf16x8*)kd, kd1 = *(const bf16x8*)(kd + 32);
      bf16x8 ko0 = *(const bf16x8*)ko, ko1 = *(const bf16x8*)(ko + 32);
      float sd = 0.f, so = 0.f;
#pragma unroll
      for (int j = 0; j < 8; j++) {
        sd = fmaf(bf2f((ushort)qf0[j]), bf2f((ushort)kd0[j]), sd);
        sd = fmaf(bf2f((ushort)qf1[j]), bf2f((ushort)kd1[j]), sd);
        so = fmaf(bf2f((ushort)qf0[j]), bf2f((ushort)ko0[j]), so);
        so = fmaf(bf2f((ushort)qf1[j]), bf2f((ushort)ko1[j]), so);
      }
      sd += __shfl_xor(sd, 16); sd += __shfl_xor(sd, 32);
      so += __shfl_xor(so, 16); so += __shfl_xor(so, 32);
      sd *= SC2; so *= SC2;
      float nm = fmaxf(m, fmaxf(sd, so));
      float alpha = ex2(m - nm);
      float pd = ex2(sd - nm), po = ex2(so - nm);
      lsum = lsum * alpha + pd + po;
      float inv = 1.0f / lsum;
      if (rvalid) {
        ushort* ob = attn_out + (size_t)grow * 768 + h * 64;
#pragma unroll
        for (int mf = 0; mf < 4; mf++) {
          u16x4 vd = *(const u16x4*)&varr[(hb + grow) * 64 + mf * 16 + g * 4];
          u16x4 vo = *(const u16x4*)&varr[(hb + obj) * 64 + mf * 16 + g * 4];
          u16x4 pk;
#pragma unroll
          for (int r = 0; r < 4; r++)
            pk[r] = f2bf((o[mf][r] * alpha + pd * bf2f(vd[r]) + po * bf2f(vo[r])) * inv);
          *(u16x4*)(ob + mf * 16 + g * 4) = pk;
        }
      }
    }
  }
}

// ---------------- merge the three ctx column-third partials (log2-domain) ---
__global__ __launch_bounds__(256) void merge_k(const ushort* __restrict__ part01,
                                               const ushort* __restrict__ part2,
                                               ushort* __restrict__ attn_out)
{
  const int task = blockIdx.x * 4 + (threadIdx.x >> 6);   // 0..24767 = h*2064+qrow
  const int lane = threadIdx.x & 63;
  const int h = task / NCTX, qrow = task - h * NCTX;
  const ushort* p0 = part01 + (size_t)(task * 2) * 72;
  const ushort* p1 = p0 + 72;
  const ushort* p2 = part2 + (size_t)task * 72;
  const float* f0 = (const float*)(p0 + 64);
  const float* f1 = (const float*)(p1 + 64);
  const float* f2 = (const float*)(p2 + 64);
  float m0 = f0[0], l0 = f0[1], m1 = f1[0], l1 = f1[1], m2 = f2[0], l2 = f2[1];
  float M = fmaxf(fmaxf(m0, m1), m2);
  float c0 = ex2(m0 - M), c1 = ex2(m1 - M), c2 = ex2(m2 - M);
  float inv = 1.0f / (c0 * l0 + c1 * l1 + c2 * l2);
  float v = (c0 * bf2f(p0[lane]) + c1 * bf2f(p1[lane]) + c2 * bf2f(p2[lane])) * inv;
  attn_out[(size_t)qrow * 768 + h * 64 + lane] = f2bf(v);
}

// ---------------------------------------------------------------------------
extern "C" void kernel_launch(void* const* d_in, const int* in_sizes, int n_in,
                              void* d_out, int out_size, void* d_ws, size_t ws_size,
                              hipStream_t stream)
{
  const float* x       = (const float*)d_in[0];
  const int*   patch_i = (const int*)d_in[1];
  const int*   point_i = (const int*)d_in[2];
  const float* ln1w    = (const float*)d_in[3];
  const float* ln1b    = (const float*)d_in[4];
  const float* qkvw    = (const float*)d_in[5];
  const float* projw   = (const float*)d_in[6];
  const float* projb   = (const float*)d_in[7];
  const float* ln2w    = (const float*)d_in[8];
  const float* ln2b    = (const float*)d_in[9];
  const float* fc1w    = (const float*)d_in[10];
  const float* fc1b    = (const float*)d_in[11];
  const float* fc2w    = (const float*)d_in[12];
  const float* fc2b    = (const float*)d_in[13];

  char* ws = (char*)d_ws;
  ushort* wqkv = (ushort*)(ws + 0);           // 2304x768 bf16
  ushort* wproj = (ushort*)(ws + 3538944);    // 768x768
  ushort* wfc1 = (ushort*)(ws + 4718592);     // 3072x768
  ushort* wfc2 = (ushort*)(ws + 9437184);     // 768x3072
  ushort* xn   = (ushort*)(ws + 14155776);    // ln out bf16 [3088][768]
  ushort* q    = (ushort*)(ws + 18898944);    // [12][3088][64]
  ushort* k    = (ushort*)(ws + 23642112);
  ushort* v    = (ushort*)(ws + 28385280);
  ushort* vt   = (ushort*)(ws + 33128448);    // [12][64][3088]
  ushort* attn = (ushort*)(ws + 37871616);    // [3088][768] bf16
  float*  x1   = (float*)(ws + 42614784);     // [3088][768] fp32
  ushort* part01 = (ushort*)(ws + 42614784);  // ctx partials thirds 0,1 (7.1MB);
                                              //   dead before x1 written (proj)
  ushort* part2  = xn;                        // third 2 partials: xn is dead
                                              //   between qkv-GEMM and ln_k
  int*    pmm  = (int*)(ws + 52101120);       // lo16,hi16,qoff16,qcnt16,qidx1024
  ushort* h1   = q;                           // fc1 out reuses q..vt
  ushort* h2n  = xn;

  prep<<<1728 + 3088 + 1, 256, 0, stream>>>(qkvw, wqkv, x, ln1w, ln1b, xn,
                                            patch_i, point_i, pmm);
  gemmk<0, 128, 128, 1><<<dim3(18, 25), 256, 0, stream>>>(xn, wqkv, 768, q, k, v, vt,
                                                          nullptr, nullptr, nullptr, nullptr);
  attn_fused<<<NCTXB + 192 * QCH + 5184, 256, 0, stream>>>(q, k, v, vt, pmm, part01, part2, attn,
                                                           projw, fc1w, fc2w,
                                                           wproj, wfc1, wfc2);
  merge_k<<<6192, 256, 0, stream>>>(part01, part2, attn);
  gemm64<1, 1><<<dim3(12, 49), 256, 0, stream>>>(attn, wproj, 768, x1, projb, x);
  ln_k<<<3088, 256, 0, stream>>>(x1, ln2w, ln2b, h2n, fc2b, (float*)d_out);
  gemmk<2, 128, 128, 1><<<dim3(24, 25), 256, 0, stream>>>(h2n, wfc1, 768, nullptr, nullptr,
                                                          nullptr, nullptr, nullptr, fc1b, nullptr, h1);
  gemm64<4, 2><<<dim3(12, 98), 256, 0, stream>>>(h1, wfc2, 3072, (float*)d_out, nullptr, nullptr);
}